// Round 15
// baseline (187.031 us; speedup 1.0000x reference)
//
#include <hip/hip_runtime.h>
#include <hip/hip_bf16.h>

typedef unsigned int u32;
typedef __attribute__((ext_vector_type(4))) float f32x4;

#define NPAIR 32
#define NCLS  92
#define NCTX  8
#define MAXL  40
#define DIM   768
#define LSUF  31

#define MAT_ELEMS 90439680u      // 32*92*40*768  (f32 elements)
#define MASK_BASE 180879360u     // 2*MAT_ELEMS (f32 element offset)

#define NBLK_CTX  256u           // (which, pair, cls-group of 23)
#define NBLK_D1   1472u          // (which, cls, token-quad)
#define NBLK_MASK 115u           // 115*256*4 = 117760 mask elems
#define NBLK_ALL  (NBLK_CTX + NBLK_D1 + NBLK_MASK)   // 1843

// ---------------- kernel 1: MLP + attention -> 8 summed rows per (which,pair) ----------------
// 64 blocks = (which, pair); writes sums[(which*32+pair)][8][768] f32 into d_ws.
// Runs once; removes ALL weight re-reads from the store phase (R14 lesson:
// reads concurrent with the write stream cost ~proportional time).
__global__ __launch_bounds__(256) void k_prep(
    const int* __restrict__ so_ids,     // (32,2) int32
    const float* __restrict__ enti,     // (36,256)
    const float* __restrict__ meta,     // (8,768)
    const float* __restrict__ sctx,     // (8,768)
    const float* __restrict__ octx,     // (8,768)
    const float* __restrict__ W1,       // (512,256)
    const float* __restrict__ b1,       // (256)
    const float* __restrict__ W2,       // (256,1536)
    float* __restrict__ sums)           // d_ws: (64,8,768)
{
    const u32 bid = blockIdx.x;
    const u32 t = threadIdx.x;
    const u32 which = bid >> 5;
    const u32 pair = bid & 31u;
    __shared__ float arena[2824];       // so_vec 512 | h 256 | red 2048 | probs 8
    __shared__ int ids[2];

    if (t == 0) {
        bool is64 = true;
        for (int i = 1; i < 64; i += 2) is64 = is64 && (so_ids[i] == 0);
        if (is64) { ids[0] = so_ids[4 * pair]; ids[1] = so_ids[4 * pair + 2]; }
        else      { ids[0] = so_ids[2 * pair]; ids[1] = so_ids[2 * pair + 1]; }
    }
    __syncthreads();

    float* so_vec = arena;
    float* h      = arena + 512;
    float* red    = arena + 768;
    float* probs  = arena + 2816;

    so_vec[t]       = enti[ids[0] * 256 + t];
    so_vec[256 + t] = enti[ids[1] * 256 + t];
    __syncthreads();

    {
        float acc = b1[t];
        const float* w = W1 + t;
        #pragma unroll 8
        for (int k = 0; k < 512; ++k)
            acc = fmaf(so_vec[k], w[(size_t)k * 256], acc);
        h[t] = fmaxf(acc, 0.f);
    }
    __syncthreads();

    float qr[3] = {0.f, 0.f, 0.f};
    {
        const float* w = W2 + which * DIM + t;
        #pragma unroll 4
        for (int k = 0; k < 256; ++k) {
            const float hk = h[k];
            #pragma unroll
            for (int i = 0; i < 3; ++i)
                qr[i] = fmaf(hk, w[(size_t)k * 1536 + i * 256], qr[i]);
        }
    }

    #pragma unroll
    for (int c = 0; c < 8; ++c) {
        float pp = 0.f;
        #pragma unroll
        for (int i = 0; i < 3; ++i)
            pp = fmaf(qr[i], meta[c * DIM + t + 256 * i], pp);
        red[c * 256 + t] = pp;
    }
    __syncthreads();
    for (int s = 128; s > 0; s >>= 1) {
        if (t < (u32)s) {
            #pragma unroll
            for (int c = 0; c < 8; ++c)
                red[c * 256 + t] += red[c * 256 + t + s];
        }
        __syncthreads();
    }
    if (t == 0) {
        const float scale = 0.036084391824351615f;  // 1/sqrt(768)
        float sc[8], m = -1e30f;
        #pragma unroll
        for (int c = 0; c < 8; ++c) { sc[c] = red[c * 256] * scale; m = fmaxf(m, sc[c]); }
        float sum = 0.f;
        #pragma unroll
        for (int c = 0; c < 8; ++c) { sc[c] = expf(sc[c] - m); sum += sc[c]; }
        const float inv = 1.f / sum;
        #pragma unroll
        for (int c = 0; c < 8; ++c) probs[c] = sc[c] * inv;
    }
    __syncthreads();

    float pr[8];
    #pragma unroll
    for (int c = 0; c < 8; ++c) pr[c] = probs[c];
    const float* ctxg = which ? octx : sctx;
    float* dst = sums + (size_t)bid * (8u * DIM);
    #pragma unroll
    for (int i = 0; i < 3; ++i) {
        const int d = t + 256 * i;
        float a = 0.f;
        #pragma unroll
        for (int c = 0; c < 8; ++c)
            a = fmaf(pr[c], meta[c * DIM + d], a);
        #pragma unroll
        for (int j = 0; j < 8; ++j)
            dst[j * DIM + d] = ctxg[j * DIM + d] + a;
    }
}

// ---------------- kernel 2: fused materializer (R12 structure, zero recompute) ----------------
//   ctx role  : stage 24 KB of precomputed sums -> stream to 23 cls slabs (552 KB)
//   copy role : stage 12 KB prefix/suffix -> 32 pairs (384 KB)
//   mask role : tail
// NT stores throughout (R10 A/B: plain stores cost +17us).
__global__ __launch_bounds__(256) void k_mat(
    const float* __restrict__ prefix,   // (133,1,768)
    const float* __restrict__ suffix,   // (133,31,768)
    const int* __restrict__ tok_mask,   // (133,40) int32
    const float* __restrict__ sums,     // (64,8,768) in d_ws
    float* __restrict__ out)
{
    const u32 bid = blockIdx.x;
    const u32 t = threadIdx.x;
    __shared__ __align__(16) float arena[8 * DIM];   // 24 KB

    if (bid < NBLK_CTX) {
        // ---------------- ctx role ----------------
        const u32 which = bid / 128u;
        const u32 rem = bid - which * 128u;
        const u32 pair = rem / 4u;
        const u32 cg = rem & 3u;

        const f32x4* src = (const f32x4*)(sums + (size_t)(which * NPAIR + pair) * (8u * DIM));
        for (u32 u = t; u < 8u * 192u; u += 256u)     // 1536 f32x4 units (24 KB)
            *(f32x4*)(arena + u * 4u) = src[u];
        __syncthreads();

        float* base = out + (size_t)which * MAT_ELEMS
                          + ((size_t)(pair * NCLS) * MAXL + 1u) * DIM;
        for (u32 c = 0; c < 23u; ++c) {
            const u32 cls = cg * 23u + c;
            float* bc = base + (size_t)cls * (MAXL * DIM);
            #pragma unroll
            for (u32 uu = 0; uu < 6u; ++uu) {
                const u32 u = uu * 256u + t;
                __builtin_nontemporal_store(*(const f32x4*)(arena + u * 4u),
                                            (f32x4*)(bc + u * 4u));
            }
        }
    } else if (bid < NBLK_CTX + NBLK_D1) {
        // ---------------- copy role: prefix/suffix replicator (LDS-staged) ----------------
        const u32 r = bid - NBLK_CTX;
        const u32 which = r / (NCLS * 8u);
        const u32 rem = r - which * (NCLS * 8u);
        const u32 cls = rem / 8u;
        const u32 tq = rem - cls * 8u;

        for (u32 u = t; u < 4u * 192u; u += 256u) {   // 768 f32x4 units (12 KB)
            const u32 j = u / 192u;
            const u32 dpos = u - j * 192u;
            const u32 rtok = (tq == 0u) ? (j == 0u ? 0u : 8u + j) : (8u + 4u * tq + j);
            const float* src = (rtok == 0u)
                ? (prefix + (size_t)(cls + 1u) * DIM + dpos * 4u)
                : (suffix + ((size_t)(cls + 1u) * LSUF + (rtok - 9u)) * DIM + dpos * 4u);
            *(f32x4*)(arena + u * 4u) = *(const f32x4*)src;
        }
        __syncthreads();

        for (u32 pair = 0; pair < NPAIR; ++pair) {
            float* slab = out + (size_t)which * MAT_ELEMS
                              + ((size_t)(pair * NCLS + cls) * MAXL) * DIM;
            #pragma unroll
            for (u32 uu = 0; uu < 3u; ++uu) {
                const u32 u = uu * 256u + t;
                const u32 j = u / 192u;                     // wave-uniform
                const u32 dpos = u - j * 192u;
                const u32 rtok = (tq == 0u) ? (j == 0u ? 0u : 8u + j) : (8u + 4u * tq + j);
                __builtin_nontemporal_store(*(const f32x4*)(arena + u * 4u),
                    (f32x4*)(slab + (size_t)rtok * DIM + dpos * 4u));
            }
        }
    } else {
        // ---------------- mask role ----------------
        const u32 idx4 = (bid - NBLK_CTX - NBLK_D1) * 256u + t;
        const u32 m = idx4 * 4u;
        f32x4 v;
        #pragma unroll
        for (int j = 0; j < 4; ++j) {
            const u32 i = m + (u32)j;
            const u32 rw = i / 40u;
            const u32 tk = i - rw * 40u;
            const u32 cls = rw % 92u;
            v[j] = (float)tok_mask[(cls + 1u) * 40u + tk];
        }
        __builtin_nontemporal_store(v, (f32x4*)(out + MASK_BASE + m));
    }
}

extern "C" void kernel_launch(void* const* d_in, const int* in_sizes, int n_in,
                              void* d_out, int out_size, void* d_ws, size_t ws_size,
                              hipStream_t stream) {
    const int* so_ids     = (const int*)d_in[0];
    const float* enti     = (const float*)d_in[1];
    const float* prefix   = (const float*)d_in[2];
    const float* suffix   = (const float*)d_in[3];
    const int* tok_mask   = (const int*)d_in[4];
    const float* meta     = (const float*)d_in[5];
    const float* sctx     = (const float*)d_in[6];
    const float* octx     = (const float*)d_in[7];
    const float* W1       = (const float*)d_in[8];
    const float* b1       = (const float*)d_in[9];
    const float* W2       = (const float*)d_in[10];
    float* sums = (float*)d_ws;   // (64,8,768) f32 = 1.5 MB

    k_prep<<<dim3(64), dim3(256), 0, stream>>>(
        so_ids, enti, meta, sctx, octx, W1, b1, W2, sums);
    k_mat<<<dim3(NBLK_ALL), dim3(256), 0, stream>>>(
        prefix, suffix, tok_mask, sums, (float*)d_out);
}

// Round 16
// 150.154 us; speedup vs baseline: 1.2456x; 1.2456x over previous
//
#include <hip/hip_runtime.h>
#include <hip/hip_bf16.h>

typedef unsigned int u32;
typedef __attribute__((ext_vector_type(4))) float f32x4;

#define NPAIR 32
#define NCLS  92
#define NCTX  8
#define MAXL  40
#define DIM   768
#define LSUF  31

#define MAT_ELEMS 90439680u      // 32*92*40*768  (f32 elements)
#define MASK_BASE 180879360u     // 2*MAT_ELEMS (f32 element offset)

#define NBLK_CTX  256u           // cg-major: (cg of 23-cls, which, pair)
#define NBLK_D1   1472u          // tq-major: (tq, which, cls)
#define NBLK_MASK 115u           // 115*256*4 = 117760 mask elems
#define NBLK_ALL  (NBLK_CTX + NBLK_D1 + NBLK_MASK)   // 1843

// ONE kernel (R12 champion structure; R16 change = XCD-coherent bid mapping).
// Blocks sharing the same staged source data get bids congruent mod 8
// (stride 184/64 are multiples of 8) -> same XCD L2 under round-robin
// dispatch -> one first-touch LLC fetch instead of eight.
//   ctx role  : 552 KB/block (23 cls x 8 tokens x 3 KB), MLP recomputed in-block
//   copy role : 384 KB/block (12 KB staged once -> 32 pairs)
//   mask role : tail
// NT stores throughout (R10 A/B: plain stores cost +17us).
__global__ __launch_bounds__(256) void k_fused(
    const int* __restrict__ so_ids,     // (32,2) int32
    const float* __restrict__ enti,     // (36,256)
    const float* __restrict__ prefix,   // (133,1,768)
    const float* __restrict__ suffix,   // (133,31,768)
    const int* __restrict__ tok_mask,   // (133,40) int32
    const float* __restrict__ meta,     // (8,768)
    const float* __restrict__ sctx,     // (8,768)
    const float* __restrict__ octx,     // (8,768)
    const float* __restrict__ W1,       // (512,256)
    const float* __restrict__ b1,       // (256)
    const float* __restrict__ W2,       // (256,1536)
    float* __restrict__ out)
{
    const u32 bid = blockIdx.x;
    const u32 t = threadIdx.x;
    __shared__ __align__(16) float arena[8 * DIM];   // 24 KB
    __shared__ int ids[2];

    if (bid < NBLK_CTX) {
        // ---------------- ctx role (cg-major: stride 64 ≡ 0 mod 8) ----------------
        const u32 cg = bid / 64u;         // 0..3 (23 cls each)
        const u32 r2 = bid - cg * 64u;
        const u32 which = r2 >> 5;
        const u32 pair = r2 & 31u;

        if (t == 0) {
            bool is64 = true;
            for (int i = 1; i < 64; i += 2) is64 = is64 && (so_ids[i] == 0);
            if (is64) { ids[0] = so_ids[4 * pair]; ids[1] = so_ids[4 * pair + 2]; }
            else      { ids[0] = so_ids[2 * pair]; ids[1] = so_ids[2 * pair + 1]; }
        }
        __syncthreads();

        float* so_vec = arena;            // [0, 512)
        float* h      = arena + 512;      // [512, 768)
        float* red    = arena + 768;      // [768, 2816)  8x256
        float* probs  = arena + 2816;     // [2816, 2824)

        so_vec[t]        = enti[ids[0] * 256 + t];
        so_vec[256 + t]  = enti[ids[1] * 256 + t];
        __syncthreads();

        // h = relu(so @ W1 + b1): thread t owns column t
        {
            float acc = b1[t];
            const float* w = W1 + t;
            #pragma unroll 8
            for (int k = 0; k < 512; ++k)
                acc = fmaf(so_vec[k], w[(size_t)k * 256], acc);
            h[t] = fmaxf(acc, 0.f);
        }
        __syncthreads();

        // q = (h @ W2)[which*768 ..]: thread t owns cols t, t+256, t+512 (regs)
        float qr[3] = {0.f, 0.f, 0.f};
        {
            const float* w = W2 + which * DIM + t;
            #pragma unroll 4
            for (int k = 0; k < 256; ++k) {
                const float hk = h[k];
                #pragma unroll
                for (int i = 0; i < 3; ++i)
                    qr[i] = fmaf(hk, w[(size_t)k * 1536 + i * 256], qr[i]);
            }
        }

        // scores vs 8 meta rows
        #pragma unroll
        for (int c = 0; c < 8; ++c) {
            float pp = 0.f;
            #pragma unroll
            for (int i = 0; i < 3; ++i)
                pp = fmaf(qr[i], meta[c * DIM + t + 256 * i], pp);
            red[c * 256 + t] = pp;
        }
        __syncthreads();
        for (int s = 128; s > 0; s >>= 1) {
            if (t < (u32)s) {
                #pragma unroll
                for (int c = 0; c < 8; ++c)
                    red[c * 256 + t] += red[c * 256 + t + s];
            }
            __syncthreads();
        }
        if (t == 0) {
            const float scale = 0.036084391824351615f;  // 1/sqrt(768)
            float sc[8], m = -1e30f;
            #pragma unroll
            for (int c = 0; c < 8; ++c) { sc[c] = red[c * 256] * scale; m = fmaxf(m, sc[c]); }
            float sum = 0.f;
            #pragma unroll
            for (int c = 0; c < 8; ++c) { sc[c] = expf(sc[c] - m); sum += sc[c]; }
            const float inv = 1.f / sum;
            #pragma unroll
            for (int c = 0; c < 8; ++c) probs[c] = sc[c] * inv;
        }
        __syncthreads();

        float pr[8];
        #pragma unroll
        for (int c = 0; c < 8; ++c) pr[c] = probs[c];
        float att_d[3];
        #pragma unroll
        for (int i = 0; i < 3; ++i) {
            const int d = t + 256 * i;
            float a = 0.f;
            #pragma unroll
            for (int c = 0; c < 8; ++c)
                a = fmaf(pr[c], meta[c * DIM + d], a);
            att_d[i] = a;
        }
        __syncthreads();   // arena fully dead

        // build the 8 summed rows (ctx + att) in LDS
        const float* ctxg = which ? octx : sctx;
        #pragma unroll
        for (int j = 0; j < 8; ++j) {
            #pragma unroll
            for (int i = 0; i < 3; ++i) {
                const int d = t + 256 * i;
                arena[j * DIM + d] = ctxg[j * DIM + d] + att_d[i];
            }
        }
        __syncthreads();

        // stream the 24 KB block to this block's 23 cls slabs (tokens 1..8)
        float* base = out + (size_t)which * MAT_ELEMS
                          + ((size_t)(pair * NCLS) * MAXL + 1u) * DIM;
        for (u32 c = 0; c < 23u; ++c) {
            const u32 cls = cg * 23u + c;
            float* bc = base + (size_t)cls * (MAXL * DIM);
            #pragma unroll
            for (u32 uu = 0; uu < 6u; ++uu) {
                const u32 u = uu * 256u + t;
                __builtin_nontemporal_store(*(const f32x4*)(arena + u * 4u),
                                            (f32x4*)(bc + u * 4u));
            }
        }
    } else if (bid < NBLK_CTX + NBLK_D1) {
        // ---------------- copy role (tq-major: stride 184 ≡ 0 mod 8) ----------------
        const u32 r = bid - NBLK_CTX;
        const u32 tq = r / 184u;          // 0..7
        const u32 g = r - tq * 184u;      // (which, cls) group
        const u32 which = g / NCLS;
        const u32 cls = g - which * NCLS;

        for (u32 u = t; u < 4u * 192u; u += 256u) {   // 768 f32x4 units (12 KB)
            const u32 j = u / 192u;
            const u32 dpos = u - j * 192u;
            const u32 rtok = (tq == 0u) ? (j == 0u ? 0u : 8u + j) : (8u + 4u * tq + j);
            const float* src = (rtok == 0u)
                ? (prefix + (size_t)(cls + 1u) * DIM + dpos * 4u)
                : (suffix + ((size_t)(cls + 1u) * LSUF + (rtok - 9u)) * DIM + dpos * 4u);
            *(f32x4*)(arena + u * 4u) = *(const f32x4*)src;
        }
        __syncthreads();

        for (u32 pair = 0; pair < NPAIR; ++pair) {
            float* slab = out + (size_t)which * MAT_ELEMS
                              + ((size_t)(pair * NCLS + cls) * MAXL) * DIM;
            #pragma unroll
            for (u32 uu = 0; uu < 3u; ++uu) {
                const u32 u = uu * 256u + t;
                const u32 j = u / 192u;                     // wave-uniform
                const u32 dpos = u - j * 192u;
                const u32 rtok = (tq == 0u) ? (j == 0u ? 0u : 8u + j) : (8u + 4u * tq + j);
                __builtin_nontemporal_store(*(const f32x4*)(arena + u * 4u),
                    (f32x4*)(slab + (size_t)rtok * DIM + dpos * 4u));
            }
        }
    } else {
        // ---------------- mask role ----------------
        const u32 idx4 = (bid - NBLK_CTX - NBLK_D1) * 256u + t;
        const u32 m = idx4 * 4u;
        f32x4 v;
        #pragma unroll
        for (int j = 0; j < 4; ++j) {
            const u32 i = m + (u32)j;
            const u32 rw = i / 40u;
            const u32 tk = i - rw * 40u;
            const u32 cls = rw % 92u;
            v[j] = (float)tok_mask[(cls + 1u) * 40u + tk];
        }
        __builtin_nontemporal_store(v, (f32x4*)(out + MASK_BASE + m));
    }
}

extern "C" void kernel_launch(void* const* d_in, const int* in_sizes, int n_in,
                              void* d_out, int out_size, void* d_ws, size_t ws_size,
                              hipStream_t stream) {
    const int* so_ids     = (const int*)d_in[0];
    const float* enti     = (const float*)d_in[1];
    const float* prefix   = (const float*)d_in[2];
    const float* suffix   = (const float*)d_in[3];
    const int* tok_mask   = (const int*)d_in[4];
    const float* meta     = (const float*)d_in[5];
    const float* sctx     = (const float*)d_in[6];
    const float* octx     = (const float*)d_in[7];
    const float* W1       = (const float*)d_in[8];
    const float* b1       = (const float*)d_in[9];
    const float* W2       = (const float*)d_in[10];

    k_fused<<<dim3(NBLK_ALL), dim3(256), 0, stream>>>(
        so_ids, enti, prefix, suffix, tok_mask, meta, sctx, octx, W1, b1, W2,
        (float*)d_out);
}

// Round 17
// 143.127 us; speedup vs baseline: 1.3068x; 1.0491x over previous
//
#include <hip/hip_runtime.h>
#include <hip/hip_bf16.h>

typedef unsigned int u32;
typedef __attribute__((ext_vector_type(4))) float f32x4;

#define NPAIR 32
#define NCLS  92
#define NCTX  8
#define MAXL  40
#define DIM   768
#define LSUF  31

#define MAT_ELEMS 90439680u      // 32*92*40*768  (f32 elements)
#define MASK_BASE 180879360u     // 2*MAT_ELEMS (f32 element offset)

#define NBLK_CTX  256u           // (which, pair, cls-group of 23)
#define NBLK_D1   1472u          // (which, cls, token-quad)
#define NBLK_MASK 115u           // 115*256*4 = 117760 mask elems
#define NBLK_ALL  (NBLK_CTX + NBLK_D1 + NBLK_MASK)   // 1843

// CHAMPION (R12, 143.6 us): one kernel, byte-balanced blocks:
//   ctx role  : 552 KB/block (23 cls x 8 tokens x 3 KB), MLP recomputed in-block
//   copy role : 384 KB/block (12 KB staged once -> 32 pairs)
//   mask role : tail
// NT stores throughout (R10 A/B: plain stores cost +17us).
// Ledger (R7-R16): write pattern / read volume / skew / write order / XCD map /
// serial prep all tested -- this structure is the measured optimum.
__global__ __launch_bounds__(256) void k_fused(
    const int* __restrict__ so_ids,     // (32,2) int32
    const float* __restrict__ enti,     // (36,256)
    const float* __restrict__ prefix,   // (133,1,768)
    const float* __restrict__ suffix,   // (133,31,768)
    const int* __restrict__ tok_mask,   // (133,40) int32
    const float* __restrict__ meta,     // (8,768)
    const float* __restrict__ sctx,     // (8,768)
    const float* __restrict__ octx,     // (8,768)
    const float* __restrict__ W1,       // (512,256)
    const float* __restrict__ b1,       // (256)
    const float* __restrict__ W2,       // (256,1536)
    float* __restrict__ out)
{
    const u32 bid = blockIdx.x;
    const u32 t = threadIdx.x;
    __shared__ __align__(16) float arena[8 * DIM];   // 24 KB
    __shared__ int ids[2];

    if (bid < NBLK_CTX) {
        // ---------------- ctx role ----------------
        const u32 which = bid / 128u;
        const u32 rem = bid - which * 128u;
        const u32 pair = rem / 4u;
        const u32 cg = rem & 3u;

        if (t == 0) {
            bool is64 = true;
            for (int i = 1; i < 64; i += 2) is64 = is64 && (so_ids[i] == 0);
            if (is64) { ids[0] = so_ids[4 * pair]; ids[1] = so_ids[4 * pair + 2]; }
            else      { ids[0] = so_ids[2 * pair]; ids[1] = so_ids[2 * pair + 1]; }
        }
        __syncthreads();

        float* so_vec = arena;            // [0, 512)
        float* h      = arena + 512;      // [512, 768)
        float* red    = arena + 768;      // [768, 2816)  8x256
        float* probs  = arena + 2816;     // [2816, 2824)

        so_vec[t]        = enti[ids[0] * 256 + t];
        so_vec[256 + t]  = enti[ids[1] * 256 + t];
        __syncthreads();

        // h = relu(so @ W1 + b1): thread t owns column t
        {
            float acc = b1[t];
            const float* w = W1 + t;
            #pragma unroll 8
            for (int k = 0; k < 512; ++k)
                acc = fmaf(so_vec[k], w[(size_t)k * 256], acc);
            h[t] = fmaxf(acc, 0.f);
        }
        __syncthreads();

        // q = (h @ W2)[which*768 ..]: thread t owns cols t, t+256, t+512 (regs)
        float qr[3] = {0.f, 0.f, 0.f};
        {
            const float* w = W2 + which * DIM + t;
            #pragma unroll 4
            for (int k = 0; k < 256; ++k) {
                const float hk = h[k];
                #pragma unroll
                for (int i = 0; i < 3; ++i)
                    qr[i] = fmaf(hk, w[(size_t)k * 1536 + i * 256], qr[i]);
            }
        }

        // scores vs 8 meta rows
        #pragma unroll
        for (int c = 0; c < 8; ++c) {
            float pp = 0.f;
            #pragma unroll
            for (int i = 0; i < 3; ++i)
                pp = fmaf(qr[i], meta[c * DIM + t + 256 * i], pp);
            red[c * 256 + t] = pp;
        }
        __syncthreads();
        for (int s = 128; s > 0; s >>= 1) {
            if (t < (u32)s) {
                #pragma unroll
                for (int c = 0; c < 8; ++c)
                    red[c * 256 + t] += red[c * 256 + t + s];
            }
            __syncthreads();
        }
        if (t == 0) {
            const float scale = 0.036084391824351615f;  // 1/sqrt(768)
            float sc[8], m = -1e30f;
            #pragma unroll
            for (int c = 0; c < 8; ++c) { sc[c] = red[c * 256] * scale; m = fmaxf(m, sc[c]); }
            float sum = 0.f;
            #pragma unroll
            for (int c = 0; c < 8; ++c) { sc[c] = expf(sc[c] - m); sum += sc[c]; }
            const float inv = 1.f / sum;
            #pragma unroll
            for (int c = 0; c < 8; ++c) probs[c] = sc[c] * inv;
        }
        __syncthreads();

        float pr[8];
        #pragma unroll
        for (int c = 0; c < 8; ++c) pr[c] = probs[c];
        float att_d[3];
        #pragma unroll
        for (int i = 0; i < 3; ++i) {
            const int d = t + 256 * i;
            float a = 0.f;
            #pragma unroll
            for (int c = 0; c < 8; ++c)
                a = fmaf(pr[c], meta[c * DIM + d], a);
            att_d[i] = a;
        }
        __syncthreads();   // arena fully dead

        // build the 8 summed rows (ctx + att) in LDS
        const float* ctxg = which ? octx : sctx;
        #pragma unroll
        for (int j = 0; j < 8; ++j) {
            #pragma unroll
            for (int i = 0; i < 3; ++i) {
                const int d = t + 256 * i;
                arena[j * DIM + d] = ctxg[j * DIM + d] + att_d[i];
            }
        }
        __syncthreads();

        // stream the 24 KB block to this block's 23 cls slabs (tokens 1..8)
        float* base = out + (size_t)which * MAT_ELEMS
                          + ((size_t)(pair * NCLS) * MAXL + 1u) * DIM;
        for (u32 c = 0; c < 23u; ++c) {
            const u32 cls = cg * 23u + c;
            float* bc = base + (size_t)cls * (MAXL * DIM);
            #pragma unroll
            for (u32 uu = 0; uu < 6u; ++uu) {
                const u32 u = uu * 256u + t;
                __builtin_nontemporal_store(*(const f32x4*)(arena + u * 4u),
                                            (f32x4*)(bc + u * 4u));
            }
        }
    } else if (bid < NBLK_CTX + NBLK_D1) {
        // ---------------- copy role: prefix/suffix replicator (LDS-staged) ----------------
        const u32 r = bid - NBLK_CTX;
        const u32 which = r / (NCLS * 8u);
        const u32 rem = r - which * (NCLS * 8u);
        const u32 cls = rem / 8u;
        const u32 tq = rem - cls * 8u;

        for (u32 u = t; u < 4u * 192u; u += 256u) {   // 768 f32x4 units (12 KB)
            const u32 j = u / 192u;
            const u32 dpos = u - j * 192u;
            const u32 rtok = (tq == 0u) ? (j == 0u ? 0u : 8u + j) : (8u + 4u * tq + j);
            const float* src = (rtok == 0u)
                ? (prefix + (size_t)(cls + 1u) * DIM + dpos * 4u)
                : (suffix + ((size_t)(cls + 1u) * LSUF + (rtok - 9u)) * DIM + dpos * 4u);
            *(f32x4*)(arena + u * 4u) = *(const f32x4*)src;
        }
        __syncthreads();

        for (u32 pair = 0; pair < NPAIR; ++pair) {
            float* slab = out + (size_t)which * MAT_ELEMS
                              + ((size_t)(pair * NCLS + cls) * MAXL) * DIM;
            #pragma unroll
            for (u32 uu = 0; uu < 3u; ++uu) {
                const u32 u = uu * 256u + t;
                const u32 j = u / 192u;                     // wave-uniform
                const u32 dpos = u - j * 192u;
                const u32 rtok = (tq == 0u) ? (j == 0u ? 0u : 8u + j) : (8u + 4u * tq + j);
                __builtin_nontemporal_store(*(const f32x4*)(arena + u * 4u),
                    (f32x4*)(slab + (size_t)rtok * DIM + dpos * 4u));
            }
        }
    } else {
        // ---------------- mask role ----------------
        const u32 idx4 = (bid - NBLK_CTX - NBLK_D1) * 256u + t;
        const u32 m = idx4 * 4u;
        f32x4 v;
        #pragma unroll
        for (int j = 0; j < 4; ++j) {
            const u32 i = m + (u32)j;
            const u32 rw = i / 40u;
            const u32 tk = i - rw * 40u;
            const u32 cls = rw % 92u;
            v[j] = (float)tok_mask[(cls + 1u) * 40u + tk];
        }
        __builtin_nontemporal_store(v, (f32x4*)(out + MASK_BASE + m));
    }
}

extern "C" void kernel_launch(void* const* d_in, const int* in_sizes, int n_in,
                              void* d_out, int out_size, void* d_ws, size_t ws_size,
                              hipStream_t stream) {
    const int* so_ids     = (const int*)d_in[0];
    const float* enti     = (const float*)d_in[1];
    const float* prefix   = (const float*)d_in[2];
    const float* suffix   = (const float*)d_in[3];
    const int* tok_mask   = (const int*)d_in[4];
    const float* meta     = (const float*)d_in[5];
    const float* sctx     = (const float*)d_in[6];
    const float* octx     = (const float*)d_in[7];
    const float* W1       = (const float*)d_in[8];
    const float* b1       = (const float*)d_in[9];
    const float* W2       = (const float*)d_in[10];

    k_fused<<<dim3(NBLK_ALL), dim3(256), 0, stream>>>(
        so_ids, enti, prefix, suffix, tok_mask, meta, sctx, octx, W1, b1, W2,
        (float*)d_out);
}